// Round 1
// baseline (459.705 us; speedup 1.0000x reference)
//
#include <hip/hip_runtime.h>

typedef _Float16 f16;
typedef unsigned int uint;
typedef f16 f16x2 __attribute__((ext_vector_type(2)));
typedef f16 f16x8 __attribute__((ext_vector_type(8)));
typedef float f32x4 __attribute__((ext_vector_type(4)));

#define Bn 512
#define Ln 128
#define Dn 128
#define Cn 512   // 4 gates * D

__device__ __forceinline__ float fdot2f(uint a, uint b, float c) {
#if __has_builtin(__builtin_amdgcn_fdot2)
  return __builtin_amdgcn_fdot2(__builtin_bit_cast(f16x2, a),
                                __builtin_bit_cast(f16x2, b), c, false);
#else
  f16x2 av = __builtin_bit_cast(f16x2, a), bv = __builtin_bit_cast(f16x2, b);
  return c + (float)av[0] * (float)bv[0] + (float)av[1] * (float)bv[1];
#endif
}

// ---------------- embedding gather: x[b*L+t][d] = emb[ids[b*L+t]][d] ----------------
__global__ __launch_bounds__(256) void k_embed(const int* __restrict__ ids,
                                               const float* __restrict__ emb,
                                               float* __restrict__ x) {
  int g = blockIdx.x * 256 + threadIdx.x;   // float4 index
  int row = g >> 5;                         // 32 float4 per row (D=128)
  int c4 = g & 31;
  int id = ids[row];
  ((float4*)x)[g] = ((const float4*)emb)[(size_t)id * 32 + c4];
}

// ---------------- convert W (both layers) to f16 and R to transposed f16 ----------------
// Wh[l][c][d] = Wg[l][c][d];  RT[l][g][h][e][d] = Rg[l][g][h][d][e]
__global__ __launch_bounds__(256) void k_convert(const float* __restrict__ Wg,
                                                 const float* __restrict__ Rg,
                                                 f16* __restrict__ Wh,
                                                 f16* __restrict__ RT) {
  int i = blockIdx.x * 256 + threadIdx.x;
  const int nW = 2 * Cn * Dn;  // 131072
  if (i < nW) {
    Wh[i] = (f16)Wg[i];
  } else {
    int j = i - nW;  // 32768 = 2*4*4*32*32
    int dd = j & 31;
    int e  = (j >> 5) & 31;
    int hh = (j >> 10) & 3;
    int g  = (j >> 12) & 3;
    int l  = j >> 14;
    RT[j] = (f16)Rg[((((l * 4 + g) * 4 + hh) * 32 + dd) * 32) + e];
  }
}

// ---------------- layernorm per row, fp32 -> f16 ----------------
__global__ __launch_bounds__(256) void k_ln(const float* __restrict__ x,
                                            const float* __restrict__ lw,
                                            const float* __restrict__ lb,
                                            f16* __restrict__ xn) {
  int row = blockIdx.x * 4 + (threadIdx.x >> 6);
  int lane = threadIdx.x & 63;
  const float* xr = x + (size_t)row * Dn;
  float a = xr[lane], b = xr[lane + 64];
  float s1 = a + b, s2 = a * a + b * b;
  #pragma unroll
  for (int off = 32; off; off >>= 1) {
    s1 += __shfl_xor(s1, off);
    s2 += __shfl_xor(s2, off);
  }
  float mu = s1 * (1.f / 128.f);
  float var = s2 * (1.f / 128.f) - mu * mu;
  float rs = rsqrtf(var + 1e-5f);
  f16* xo = xn + (size_t)row * Dn;
  xo[lane]      = (f16)((a - mu) * rs * lw[lane] + lb[lane]);
  xo[lane + 64] = (f16)((b - mu) * rs * lw[lane + 64] + lb[lane + 64]);
}

// ---------------- GEMM: pre[t][b][c] = sum_d xn[b*L+t][d] * Wh[c][d] + bias[c] ----------------
// block = 256 thr (4 waves). Block tile M=64 (wave=16 rows), N=128. grid = (65536/64)*(512/128)=4096.
__global__ __launch_bounds__(256) void k_gemm(const f16* __restrict__ xn,
                                              const f16* __restrict__ Wh,
                                              const float* __restrict__ bias,
                                              f16* __restrict__ pre) {
  int ntile = blockIdx.x & 3;
  int mtile = blockIdx.x >> 2;
  int w = threadIdx.x >> 6;
  int lane = threadIdx.x & 63;
  int l16 = lane & 15, quad = lane >> 4;
  int m0 = mtile * 64 + w * 16;

  f32x4 acc[8] = {};
  const f16* arow = xn + (size_t)(m0 + l16) * Dn + quad * 8;
  const f16* bbase = Wh + (size_t)(ntile * 128 + l16) * Dn + quad * 8;

  #pragma unroll
  for (int kk = 0; kk < 4; ++kk) {
    f16x8 af = *(const f16x8*)(arow + kk * 32);
    #pragma unroll
    for (int i = 0; i < 8; ++i) {
      f16x8 bf = *(const f16x8*)(bbase + (size_t)i * 16 * Dn + kk * 32);
      acc[i] = __builtin_amdgcn_mfma_f32_16x16x32_f16(af, bf, acc[i], 0, 0, 0);
    }
  }
  #pragma unroll
  for (int i = 0; i < 8; ++i) {
    int col = ntile * 128 + i * 16 + l16;
    float bv = bias[col];
    #pragma unroll
    for (int r = 0; r < 4; ++r) {
      int row = m0 + quad * 4 + r;     // global M row = b*L + t
      int t = row & 127, bi = row >> 7;
      pre[((size_t)(t * Bn + bi) << 9) + col] = (f16)(acc[i][r] + bv);
    }
  }
}

// ---------------- fused scan: rec (f16 dot2) + pointwise + groupnorm + residual ----------------
// grid 256 blocks, 256 threads, 2 sequences per block; thread owns element d of its sequence.
__global__ __launch_bounds__(256) void k_scan(const f16* __restrict__ pre,
                                              const f16* __restrict__ RT,
                                              const float* __restrict__ gnw,
                                              float* __restrict__ x) {
  const int s = threadIdx.x >> 7;
  const int d = threadIdx.x & 127;
  const int head = d >> 5;
  const int e = d & 31;
  const int b = blockIdx.x * 2 + s;
  __shared__ __align__(16) f16 hsh[2][128];

  // R columns for this (head, e), all 4 gates, packed as 16 x (2 f16) each
  uint rr[4][16];
  const uint* RT32 = (const uint*)RT;
  #pragma unroll
  for (int g = 0; g < 4; ++g) {
    const uint* p = RT32 + ((g * 4 + head) * 32 + e) * 16;
    #pragma unroll
    for (int j = 0; j < 16; ++j) rr[g][j] = p[j];
  }
  const float gw = gnw[d];
  hsh[s][d] = (f16)0.f;
  __syncthreads();

  const f16* prow = pre + (size_t)b * Cn + d;             // + t*Bn*Cn + g*128
  const float* xrow = x + (size_t)b * Ln * Dn + d;        // + t*Dn
  float* xo = x + (size_t)b * Ln * Dn + d;

  float pc0 = (float)prow[0],   pc1 = (float)prow[128];
  float pc2 = (float)prow[256], pc3 = (float)prow[384];
  float xc = xrow[0];
  float cc = 0.f, nc = 0.f, mc = 0.f;

  for (int t = 0; t < Ln; ++t) {
    // prefetch next step's pre/x one iteration ahead
    int tn = (t + 1 < Ln) ? (t + 1) : t;
    const f16* pn = prow + (size_t)tn * (Bn * Cn);
    float pN0 = (float)pn[0],   pN1 = (float)pn[128];
    float pN2 = (float)pn[256], pN3 = (float)pn[384];
    float xN = xrow[(size_t)tn * Dn];

    // read h(t-1) for my head (broadcast across the 32 e-lanes)
    uint hu[16];
    {
      const uint4* hq = (const uint4*)(((const uint*)&hsh[s][0]) + head * 16);
      uint4 q0 = hq[0], q1 = hq[1], q2 = hq[2], q3 = hq[3];
      hu[0]=q0.x; hu[1]=q0.y; hu[2]=q0.z; hu[3]=q0.w;
      hu[4]=q1.x; hu[5]=q1.y; hu[6]=q1.z; hu[7]=q1.w;
      hu[8]=q2.x; hu[9]=q2.y; hu[10]=q2.z; hu[11]=q2.w;
      hu[12]=q3.x; hu[13]=q3.y; hu[14]=q3.z; hu[15]=q3.w;
    }
    float a0 = 0.f, a1 = 0.f, a2 = 0.f, a3 = 0.f;
    #pragma unroll
    for (int j = 0; j < 16; ++j) {
      a0 = fdot2f(hu[j], rr[0][j], a0);
      a1 = fdot2f(hu[j], rr[1][j], a1);
      a2 = fdot2f(hu[j], rr[2][j], a2);
      a3 = fdot2f(hu[j], rr[3][j], a3);
    }
    float it = pc0 + a0, ft = pc1 + a1, zt = pc2 + a2, ot = pc3 + a3;

    float mn = fmaxf(ft + mc, it);
    float iv = __expf(it - mn);
    float fv = __expf(ft + mc - mn);
    float zc = fminf(fmaxf(zt, -15.f), 15.f);
    float ez = __expf(2.f * zc);
    float tz = (ez - 1.f) * __builtin_amdgcn_rcpf(ez + 1.f);
    float cn = fv * cc + iv * tz;
    float nn = fv * nc + iv;
    float sg = __builtin_amdgcn_rcpf(1.f + __expf(-ot));
    float hn = sg * cn * __builtin_amdgcn_rcpf(nn);
    cc = cn; nc = nn; mc = mn;

    // groupnorm over the 32-lane head group + residual
    float s1 = hn, s2 = hn * hn;
    #pragma unroll
    for (int off = 16; off; off >>= 1) {
      s1 += __shfl_xor(s1, off);
      s2 += __shfl_xor(s2, off);
    }
    float mu = s1 * (1.f / 32.f);
    float va = s2 * (1.f / 32.f) - mu * mu;
    float ov = xc + (hn - mu) * rsqrtf(va + 1e-5f) * gw;
    xo[(size_t)t * Dn] = ov;

    __syncthreads();            // all reads of old h done
    hsh[s][d] = (f16)hn;
    __syncthreads();            // new h visible

    pc0 = pN0; pc1 = pN1; pc2 = pN2; pc3 = pN3; xc = xN;
  }
}

// ---------------- head: mean-pool over t, 2-layer MLP ----------------
__global__ __launch_bounds__(128) void k_head(const float* __restrict__ x,
                                              const float* __restrict__ w1,
                                              const float* __restrict__ b1,
                                              const float* __restrict__ w2,
                                              const float* __restrict__ b2,
                                              float* __restrict__ out) {
  int b = blockIdx.x;
  int tid = threadIdx.x;  // 128
  const float* xb = x + (size_t)b * Ln * Dn;
  float s = 0.f;
  for (int t = 0; t < Ln; ++t) s += xb[(size_t)t * Dn + tid];
  __shared__ float pool[128];
  __shared__ float hid[64];
  pool[tid] = s * (1.f / 128.f);
  __syncthreads();
  if (tid < 64) {
    float a = b1[tid];
    const float* wr = w1 + (size_t)tid * Dn;
    #pragma unroll 4
    for (int dd = 0; dd < Dn; ++dd) a += pool[dd] * wr[dd];
    hid[tid] = fmaxf(a, 0.f);
  }
  __syncthreads();
  if (tid < 2) {
    float a = b2[tid];
    const float* wr = w2 + tid * 64;
    #pragma unroll 4
    for (int j = 0; j < 64; ++j) a += hid[j] * wr[j];
    out[b * 2 + tid] = a;
  }
}

extern "C" void kernel_launch(void* const* d_in, const int* in_sizes, int n_in,
                              void* d_out, int out_size, void* d_ws, size_t ws_size,
                              hipStream_t stream) {
  const int*   ids  = (const int*)d_in[0];
  const float* emb  = (const float*)d_in[1];
  const float* ln_w = (const float*)d_in[2];
  const float* ln_b = (const float*)d_in[3];
  const float* Wg   = (const float*)d_in[4];
  const float* Rg   = (const float*)d_in[5];
  const float* bg   = (const float*)d_in[6];
  const float* gn_w = (const float*)d_in[7];
  const float* w1   = (const float*)d_in[8];
  const float* b1   = (const float*)d_in[9];
  const float* w2   = (const float*)d_in[10];
  const float* b2   = (const float*)d_in[11];
  float* out = (float*)d_out;

  char* ws = (char*)d_ws;
  float* x   = (float*)ws;                                  // 33,554,432 B
  f16*   xn  = (f16*)(ws + 33554432);                       // 16,777,216 B
  f16*   pre = (f16*)(ws + 33554432 + 16777216);            // 67,108,864 B
  f16*   Wh  = (f16*)(ws + 117440512);                      //    262,144 B
  f16*   RT  = (f16*)(ws + 117440512 + 262144);             //     65,536 B

  k_embed<<<8192, 256, 0, stream>>>(ids, emb, x);
  k_convert<<<640, 256, 0, stream>>>(Wg, Rg, Wh, RT);
  for (int l = 0; l < 2; ++l) {
    k_ln<<<16384, 256, 0, stream>>>(x, ln_w + l * Dn, ln_b + l * Dn, xn);
    k_gemm<<<4096, 256, 0, stream>>>(xn, Wh + (size_t)l * Cn * Dn, bg + l * Cn, pre);
    k_scan<<<256, 256, 0, stream>>>(pre, RT + (size_t)l * 16384, gn_w + l * Dn, x);
  }
  k_head<<<512, 128, 0, stream>>>(x, w1, b1, w2, b2, out);
}

// Round 2
// 454.428 us; speedup vs baseline: 1.0116x; 1.0116x over previous
//
#include <hip/hip_runtime.h>

typedef _Float16 f16;
typedef unsigned int uint;
typedef f16 f16x2 __attribute__((ext_vector_type(2)));
typedef f16 f16x8 __attribute__((ext_vector_type(8)));
typedef float f32x4 __attribute__((ext_vector_type(4)));

#define Bn 512
#define Ln 128
#define Dn 128
#define Cn 512   // 4 gates * D

__device__ __forceinline__ float fdot2f(uint a, uint b, float c) {
#if __has_builtin(__builtin_amdgcn_fdot2)
  return __builtin_amdgcn_fdot2(__builtin_bit_cast(f16x2, a),
                                __builtin_bit_cast(f16x2, b), c, false);
#else
  f16x2 av = __builtin_bit_cast(f16x2, a), bv = __builtin_bit_cast(f16x2, b);
  return c + (float)av[0] * (float)bv[0] + (float)av[1] * (float)bv[1];
#endif
}

// ---------------- embedding gather: x[b*L+t][d] = emb[ids[b*L+t]][d] ----------------
__global__ __launch_bounds__(256) void k_embed(const int* __restrict__ ids,
                                               const float* __restrict__ emb,
                                               float* __restrict__ x) {
  int g = blockIdx.x * 256 + threadIdx.x;   // float4 index
  int row = g >> 5;                         // 32 float4 per row (D=128)
  int c4 = g & 31;
  int id = ids[row];
  ((float4*)x)[g] = ((const float4*)emb)[(size_t)id * 32 + c4];
}

// ---------------- convert W (both layers) to f16 and R to transposed f16 ----------------
// Wh[l][c][d] = Wg[l][c][d];  RT[l][g][h][e][d] = Rg[l][g][h][d][e]
__global__ __launch_bounds__(256) void k_convert(const float* __restrict__ Wg,
                                                 const float* __restrict__ Rg,
                                                 f16* __restrict__ Wh,
                                                 f16* __restrict__ RT) {
  int i = blockIdx.x * 256 + threadIdx.x;
  const int nW = 2 * Cn * Dn;  // 131072
  if (i < nW) {
    Wh[i] = (f16)Wg[i];
  } else {
    int j = i - nW;  // 32768 = 2*4*4*32*32
    int dd = j & 31;
    int e  = (j >> 5) & 31;
    int hh = (j >> 10) & 3;
    int g  = (j >> 12) & 3;
    int l  = j >> 14;
    RT[j] = (f16)Rg[((((l * 4 + g) * 4 + hh) * 32 + dd) * 32) + e];
  }
}

// ---------------- layernorm per row, fp32 -> f16 ----------------
__global__ __launch_bounds__(256) void k_ln(const float* __restrict__ x,
                                            const float* __restrict__ lw,
                                            const float* __restrict__ lb,
                                            f16* __restrict__ xn) {
  int row = blockIdx.x * 4 + (threadIdx.x >> 6);
  int lane = threadIdx.x & 63;
  const float* xr = x + (size_t)row * Dn;
  float a = xr[lane], b = xr[lane + 64];
  float s1 = a + b, s2 = a * a + b * b;
  #pragma unroll
  for (int off = 32; off; off >>= 1) {
    s1 += __shfl_xor(s1, off);
    s2 += __shfl_xor(s2, off);
  }
  float mu = s1 * (1.f / 128.f);
  float var = s2 * (1.f / 128.f) - mu * mu;
  float rs = rsqrtf(var + 1e-5f);
  f16* xo = xn + (size_t)row * Dn;
  xo[lane]      = (f16)((a - mu) * rs * lw[lane] + lb[lane]);
  xo[lane + 64] = (f16)((b - mu) * rs * lw[lane + 64] + lb[lane + 64]);
}

// ---------------- GEMM: pre[m][c] = sum_d xn[m][d] * Wh[c][d] + bias[c], m = b*L+t ----------------
// block = 256 thr (4 waves). Block tile M=64 (wave=16 rows), N=128.
// Epilogue stages through LDS (padded) for 256B-contiguous f16x8 stores.
__global__ __launch_bounds__(256) void k_gemm(const f16* __restrict__ xn,
                                              const f16* __restrict__ Wh,
                                              const float* __restrict__ bias,
                                              f16* __restrict__ pre) {
  int ntile = blockIdx.x & 3;
  int mtile = blockIdx.x >> 2;
  int w = threadIdx.x >> 6;
  int lane = threadIdx.x & 63;
  int l16 = lane & 15, quad = lane >> 4;
  int m0 = mtile * 64 + w * 16;

  __shared__ __align__(16) f16 tile[64 * 136];   // 136-col pad: quad rows hit disjoint bank groups

  f32x4 acc[8] = {};
  const f16* arow = xn + (size_t)(m0 + l16) * Dn + quad * 8;
  const f16* bbase = Wh + (size_t)(ntile * 128 + l16) * Dn + quad * 8;

  #pragma unroll
  for (int kk = 0; kk < 4; ++kk) {
    f16x8 af = *(const f16x8*)(arow + kk * 32);
    #pragma unroll
    for (int i = 0; i < 8; ++i) {
      f16x8 bf = *(const f16x8*)(bbase + (size_t)i * 16 * Dn + kk * 32);
      acc[i] = __builtin_amdgcn_mfma_f32_16x16x32_f16(af, bf, acc[i], 0, 0, 0);
    }
  }
  #pragma unroll
  for (int i = 0; i < 8; ++i) {
    float bv = bias[ntile * 128 + i * 16 + l16];
    #pragma unroll
    for (int r = 0; r < 4; ++r) {
      int rl = w * 16 + quad * 4 + r;      // local row 0..63
      tile[rl * 136 + i * 16 + l16] = (f16)(acc[i][r] + bv);
    }
  }
  __syncthreads();
  // 64 rows x 128 f16 (256B) -> pre[(m0base+row)*512 + ntile*128 ...]
  int m0base = mtile * 64;
  #pragma unroll
  for (int it = 0; it < 4; ++it) {
    int chunk = it * 256 + threadIdx.x;    // 0..1023 chunks of 16B
    int row = chunk >> 4;
    int c16 = chunk & 15;
    f16x8 v = *(const f16x8*)&tile[row * 136 + c16 * 8];
    *(f16x8*)&pre[(size_t)(m0base + row) * Cn + ntile * 128 + c16 * 8] = v;
  }
}

// ---------------- fused scan: barrier-free, wave-local h exchange ----------------
// Each wave owns 2 (seq,head) groups (32 lanes each). Recurrence is block-diagonal
// per head, so h exchange stays inside the wave: LDS write/read with per-wave DS
// ordering, NO __syncthreads in the time loop.
// grid 256 blocks x 256 threads; block = 2 seqs x 4 heads.
__global__ __launch_bounds__(256) void k_scan(const f16* __restrict__ pre,
                                              const f16* __restrict__ RT,
                                              const float* __restrict__ gnw,
                                              float* __restrict__ x) {
  const int w = threadIdx.x >> 6;       // wave 0..3
  const int lane = threadIdx.x & 63;
  const int s = w >> 1;                 // seq within block
  const int b = blockIdx.x * 2 + s;
  const int d = ((w & 1) << 6) + lane;  // element 0..127 of this seq
  const int head = d >> 5;
  const int e = d & 31;
  const int half = lane >> 5;

  __shared__ __align__(16) f16 hsh[4][64];   // per-wave h exchange (128B each)

  // R columns for this (head, e), all 4 gates, packed as 16 x (2 f16)
  uint rr[4][16];
  const uint* RT32 = (const uint*)RT;
  #pragma unroll
  for (int g = 0; g < 4; ++g) {
    const uint* p = RT32 + ((g * 4 + head) * 32 + e) * 16;
    #pragma unroll
    for (int j = 0; j < 16; ++j) rr[g][j] = p[j];
  }
  const float gw = gnw[d];
  hsh[w][lane] = (f16)0.f;   // same wave writes & reads -> DS in-order, no barrier

  const f16* prow = pre + ((size_t)b * Ln) * Cn + d;      // + t*Cn + g*128
  const float* xrow = x + (size_t)b * Ln * Dn + d;        // + t*Dn
  float* xo = x + (size_t)b * Ln * Dn + d;

  float pc0 = (float)prow[0],   pc1 = (float)prow[128];
  float pc2 = (float)prow[256], pc3 = (float)prow[384];
  float xc = xrow[0];
  float cc = 0.f, nc = 0.f, mc = 0.f;

  for (int t = 0; t < Ln; ++t) {
    // prefetch next step's pre/x
    int tn = (t + 1 < Ln) ? (t + 1) : t;
    const f16* pn = prow + (size_t)tn * Cn;
    float pN0 = (float)pn[0],   pN1 = (float)pn[128];
    float pN2 = (float)pn[256], pN3 = (float)pn[384];
    float xN = xrow[(size_t)tn * Dn];

    // read h(t-1) for my group (broadcast across the 32 e-lanes of the half-wave)
    uint hu[16];
    {
      const uint4* hq = (const uint4*)(((const uint*)&hsh[w][0]) + half * 16);
      uint4 q0 = hq[0], q1 = hq[1], q2 = hq[2], q3 = hq[3];
      hu[0]=q0.x; hu[1]=q0.y; hu[2]=q0.z; hu[3]=q0.w;
      hu[4]=q1.x; hu[5]=q1.y; hu[6]=q1.z; hu[7]=q1.w;
      hu[8]=q2.x; hu[9]=q2.y; hu[10]=q2.z; hu[11]=q2.w;
      hu[12]=q3.x; hu[13]=q3.y; hu[14]=q3.z; hu[15]=q3.w;
    }
    float a0 = 0.f, a1 = 0.f, a2 = 0.f, a3 = 0.f;
    #pragma unroll
    for (int j = 0; j < 16; ++j) {
      a0 = fdot2f(hu[j], rr[0][j], a0);
      a1 = fdot2f(hu[j], rr[1][j], a1);
      a2 = fdot2f(hu[j], rr[2][j], a2);
      a3 = fdot2f(hu[j], rr[3][j], a3);
    }
    float it = pc0 + a0, ft = pc1 + a1, zt = pc2 + a2, ot = pc3 + a3;

    float mn = fmaxf(ft + mc, it);
    float iv = __expf(it - mn);
    float fv = __expf(ft + mc - mn);
    float zc = fminf(fmaxf(zt, -15.f), 15.f);
    float ez = __expf(2.f * zc);
    float tz = (ez - 1.f) * __builtin_amdgcn_rcpf(ez + 1.f);
    float cn = fv * cc + iv * tz;
    float nn = fv * nc + iv;
    float sg = __builtin_amdgcn_rcpf(1.f + __expf(-ot));
    float hn = sg * cn * __builtin_amdgcn_rcpf(nn);
    cc = cn; nc = nn; mc = mn;

    // next-step h exchange (wave-local, no barrier)
    hsh[w][lane] = (f16)hn;

    // groupnorm over the 32-lane head group + residual (off the recurrence path)
    float s1 = hn, s2 = hn * hn;
    #pragma unroll
    for (int off = 16; off; off >>= 1) {
      s1 += __shfl_xor(s1, off);
      s2 += __shfl_xor(s2, off);
    }
    float mu = s1 * (1.f / 32.f);
    float va = s2 * (1.f / 32.f) - mu * mu;
    float ov = xc + (hn - mu) * rsqrtf(va + 1e-5f) * gw;
    xo[(size_t)t * Dn] = ov;

    pc0 = pN0; pc1 = pN1; pc2 = pN2; pc3 = pN3; xc = xN;
  }
}

// ---------------- head: mean-pool over t, 2-layer MLP ----------------
__global__ __launch_bounds__(128) void k_head(const float* __restrict__ x,
                                              const float* __restrict__ w1,
                                              const float* __restrict__ b1,
                                              const float* __restrict__ w2,
                                              const float* __restrict__ b2,
                                              float* __restrict__ out) {
  int b = blockIdx.x;
  int tid = threadIdx.x;  // 128
  const float* xb = x + (size_t)b * Ln * Dn;
  float s = 0.f;
  for (int t = 0; t < Ln; ++t) s += xb[(size_t)t * Dn + tid];
  __shared__ float pool[128];
  __shared__ float hid[64];
  pool[tid] = s * (1.f / 128.f);
  __syncthreads();
  if (tid < 64) {
    float a = b1[tid];
    const float* wr = w1 + (size_t)tid * Dn;
    #pragma unroll 4
    for (int dd = 0; dd < Dn; ++dd) a += pool[dd] * wr[dd];
    hid[tid] = fmaxf(a, 0.f);
  }
  __syncthreads();
  if (tid < 2) {
    float a = b2[tid];
    const float* wr = w2 + tid * 64;
    #pragma unroll 4
    for (int j = 0; j < 64; ++j) a += hid[j] * wr[j];
    out[b * 2 + tid] = a;
  }
}

extern "C" void kernel_launch(void* const* d_in, const int* in_sizes, int n_in,
                              void* d_out, int out_size, void* d_ws, size_t ws_size,
                              hipStream_t stream) {
  const int*   ids  = (const int*)d_in[0];
  const float* emb  = (const float*)d_in[1];
  const float* ln_w = (const float*)d_in[2];
  const float* ln_b = (const float*)d_in[3];
  const float* Wg   = (const float*)d_in[4];
  const float* Rg   = (const float*)d_in[5];
  const float* bg   = (const float*)d_in[6];
  const float* gn_w = (const float*)d_in[7];
  const float* w1   = (const float*)d_in[8];
  const float* b1   = (const float*)d_in[9];
  const float* w2   = (const float*)d_in[10];
  const float* b2   = (const float*)d_in[11];
  float* out = (float*)d_out;

  char* ws = (char*)d_ws;
  float* x   = (float*)ws;                                  // 33,554,432 B
  f16*   xn  = (f16*)(ws + 33554432);                       // 16,777,216 B
  f16*   pre = (f16*)(ws + 33554432 + 16777216);            // 67,108,864 B
  f16*   Wh  = (f16*)(ws + 117440512);                      //    262,144 B
  f16*   RT  = (f16*)(ws + 117440512 + 262144);             //     65,536 B

  k_embed<<<8192, 256, 0, stream>>>(ids, emb, x);
  k_convert<<<640, 256, 0, stream>>>(Wg, Rg, Wh, RT);
  for (int l = 0; l < 2; ++l) {
    k_ln<<<16384, 256, 0, stream>>>(x, ln_w + l * Dn, ln_b + l * Dn, xn);
    k_gemm<<<4096, 256, 0, stream>>>(xn, Wh + (size_t)l * Cn * Dn, bg + l * Cn, pre);
    k_scan<<<256, 256, 0, stream>>>(pre, RT + (size_t)l * 16384, gn_w + l * Dn, x);
  }
  k_head<<<512, 128, 0, stream>>>(x, w1, b1, w2, b2, out);
}